// Round 1
// baseline (782.845 us; speedup 1.0000x reference)
//
#include <hip/hip_runtime.h>
#include <stdint.h>

#define TOL  1e-2f
#define WPB  4      // waves per block
#define AUGS 68     // augmented-row stride in floats (16B-aligned rows)

__device__ __forceinline__ float bcastf(float v, int l) {
    return __int_as_float(__builtin_amdgcn_readlane(__float_as_int(v), l));
}

// mode 0: run (max_iter-1) steps, record per-step (residual >= TOL) bitmask.
// mode 1: run *steps_ptr steps, write u_star and z_star.
__global__ __launch_bounds__(256) void dys_pass(
    const float* __restrict__ u_nom,     // (B,16)
    const float* __restrict__ Amat,      // (B,32,16)
    const float* __restrict__ bvec,      // (B,32)
    const int*   __restrict__ mi_ptr,    // max_iter (scalar)
    unsigned long long* __restrict__ flags,  // ws: 2x u64
    const int*   __restrict__ steps_ptr,     // ws+16: step count for pass 2
    float*       __restrict__ out,
    int mode)
{
    __shared__ float aug_s[WPB][32][AUGS];
    const int tid  = threadIdx.x;
    const int lane = tid & 63;
    const int wib  = tid >> 6;
    const int elem = blockIdx.x * WPB + wib;
    float (*aug)[AUGS] = aug_s[wib];

    const int  row   = lane & 31;
    const int  col16 = lane & 15;
    const bool lower = lane < 32;

    // ---- load A row (row = lane&31) into registers, coalesced float4 ----
    const float* Ab = Amat + (size_t)elem * 512 + (size_t)row * 16;
    float A_row[16];
    {
        float4 a0 = ((const float4*)Ab)[0];
        float4 a1 = ((const float4*)Ab)[1];
        float4 a2 = ((const float4*)Ab)[2];
        float4 a3 = ((const float4*)Ab)[3];
        A_row[0]=a0.x;  A_row[1]=a0.y;  A_row[2]=a0.z;  A_row[3]=a0.w;
        A_row[4]=a1.x;  A_row[5]=a1.y;  A_row[6]=a1.z;  A_row[7]=a1.w;
        A_row[8]=a2.x;  A_row[9]=a2.y;  A_row[10]=a2.z; A_row[11]=a2.w;
        A_row[12]=a3.x; A_row[13]=a3.y; A_row[14]=a3.z; A_row[15]=a3.w;
    }
    const float un = u_nom[(size_t)elem * 16 + col16];
    const float bv = bvec[(size_t)elem * 32 + row];

    // ---- stage A rows into aug cols 32..47 so upper lanes can grab columns ----
    if (lower) {
        #pragma unroll
        for (int k = 0; k < 16; ++k) aug[row][32 + k] = A_row[k];
    }
    __syncthreads();

    // mat: lanes<32 -> N^-1 row `lane` (filled after GJ); lanes>=32 -> A column (lane&15)
    float mat[32];
    if (!lower) {
        #pragma unroll
        for (int i = 0; i < 32; ++i) mat[i] = aug[i][32 + col16];
    }
    __syncthreads();

    // ---- N = 2*A*A^T + I into cols 0..31 (lower lanes), identity into 32..63 (upper) ----
    #pragma unroll 4
    for (int j = 0; j < 32; ++j) {
        float acc = 0.f;
        #pragma unroll
        for (int k = 0; k < 16; ++k)
            acc = fmaf(bcastf(A_row[k], j), A_row[k], acc);   // dot(row j, row lane)
        float nv  = 2.f * acc + ((j == lane) ? 1.f : 0.f);
        float idv = ((lane - 32) == j) ? 1.f : 0.f;
        aug[j][lane] = lower ? nv : idv;
    }
    __syncthreads();

    // ---- Gauss-Jordan inversion (SPD, eigenvalues >= 1 -> no pivoting needed) ----
    for (int p = 0; p < 32; ++p) {
        float rp  = aug[p][lane];
        float piv = bcastf(rp, p);
        rp = rp / piv;
        aug[p][lane] = rp;
        #pragma unroll 8
        for (int i = 0; i < 32; ++i) {
            if (i == p) continue;
            float f = aug[i][p];                 // lane-uniform LDS broadcast read
            aug[i][lane] = fmaf(-f, rp, aug[i][lane]);
        }
        __syncthreads();
    }

    if (lower) {
        #pragma unroll
        for (int i = 0; i < 32; ++i) mat[i] = aug[lane][32 + i];  // N^-1 row
    }

    const int mi     = *mi_ptr;
    const int nsteps = (mode == 0) ? (mi - 1) : *steps_ptr;

    float z = 0.f;
    unsigned long long m0 = 0ull, m1 = 0ull;

    for (int k = 1; k <= nsteps; ++k) {
        float x   = fmaxf(z, 0.f);
        float x16 = __shfl(x, lane + 16);
        float z16 = __shfl(z, lane + 16);
        float d = (x - x16) - un;                       // lanes 0..15
        float s = (x - x16) - (z - z16) + un;           // lanes 0..15
        float v3 = __shfl(fmaf(2.f, x, -z), lane + 32); // lanes 0..31

        // g = A s + v3 - b            (valid on lanes 0..31)
        float g = v3 - bv, g2 = 0.f;
        #pragma unroll
        for (int kk = 0; kk < 16; kk += 2) {
            g  = fmaf(A_row[kk],     bcastf(s, kk),     g);
            g2 = fmaf(A_row[kk + 1], bcastf(s, kk + 1), g2);
        }
        g += g2;

        // w = N^-1 g                  (valid on lanes 0..31)
        float w = 0.f, w2 = 0.f;
        #pragma unroll
        for (int i = 0; i < 32; i += 2) {
            w  = fmaf(mat[i],     bcastf(g, i),     w);
            w2 = fmaf(mat[i + 1], bcastf(g, i + 1), w2);
        }
        w += w2;

        // t = A^T w                   (valid on lanes 32..47; 48..63 duplicate)
        float t = 0.f, t2 = 0.f;
        #pragma unroll
        for (int j = 0; j < 32; j += 2) {
            t  = fmaf(mat[j],     bcastf(w, j),     t);
            t2 = fmaf(mat[j + 1], bcastf(w, j + 1), t2);
        }
        t += t2;

        float dd = __shfl(d, col16);        // d[k] everywhere
        float tt = __shfl(t, 32 + col16);   // t[k] everywhere
        float ww = __shfl(w, row);          // w[j] everywhere
        float upd = lower ? ((lane < 16) ? -(0.5f * dd + tt) : (0.5f * dd + tt))
                          : (-ww);
        float znew = x + upd;

        if (mode == 0) {
            float r = fabsf(znew - z);
            #pragma unroll
            for (int moff = 32; moff >= 1; moff >>= 1)
                r = fmaxf(r, __shfl_xor(r, moff));
            unsigned long long bit = (r >= TOL) ? 1ull : 0ull;
            if (k < 64) m0 |= bit << k; else m1 |= bit << (k - 64);
        }
        z = znew;
    }

    if (mode == 0) {
        if (lane == 0) {
            atomicOr(flags,     m0);
            atomicOr(flags + 1, m1);
        }
    } else {
        float z16b = __shfl(z, lane + 16);
        size_t B = (size_t)gridDim.x * WPB;
        if (lane < 16) out[(size_t)elem * 16 + lane] = z - z16b;   // u_star
        out[B * 16 + (size_t)elem * 64 + lane] = z;                // z_star
    }
}

// Derive the reference's global stopping step count:
// K = first k in [1, mi-1] with (global max residual at step k) < TOL, else mi-1.
// Total T applications S = K + 1.
__global__ void dys_reduce(const int* __restrict__ mi_ptr,
                           const unsigned long long* __restrict__ flags,
                           int* __restrict__ steps)
{
    int mi = *mi_ptr;
    unsigned long long m0 = flags[0], m1 = flags[1];
    int S = mi;                     // never converged: K = mi-1 -> S = mi
    for (int k = 1; k < mi; ++k) {
        unsigned long long bit = (k < 64) ? ((m0 >> k) & 1ull)
                                          : ((m1 >> (k - 64)) & 1ull);
        if (!bit) { S = k + 1; break; }
    }
    if (S < 1) S = 1;
    *steps = S;
}

extern "C" void kernel_launch(void* const* d_in, const int* in_sizes, int n_in,
                              void* d_out, int out_size, void* d_ws, size_t ws_size,
                              hipStream_t stream) {
    (void)n_in; (void)out_size; (void)ws_size;
    const float* u_nom = (const float*)d_in[0];
    const float* Amat  = (const float*)d_in[1];
    const float* bvec  = (const float*)d_in[2];
    const int*   mi    = (const int*)d_in[3];

    const int B = in_sizes[0] / 16;          // 8192
    unsigned long long* flags = (unsigned long long*)d_ws;
    int* steps = (int*)((char*)d_ws + 16);

    hipMemsetAsync(d_ws, 0, 32, stream);     // flags + steps (ws is poisoned 0xAA)

    const int blocks = B / WPB;
    dys_pass<<<blocks, 64 * WPB, 0, stream>>>(u_nom, Amat, bvec, mi, flags, steps,
                                              (float*)d_out, 0);
    dys_reduce<<<1, 1, 0, stream>>>(mi, flags, steps);
    dys_pass<<<blocks, 64 * WPB, 0, stream>>>(u_nom, Amat, bvec, mi, flags, steps,
                                              (float*)d_out, 1);
}

// Round 2
// 318.232 us; speedup vs baseline: 2.4600x; 2.4600x over previous
//
#include <hip/hip_runtime.h>
#include <stdint.h>

#define TOL 1e-2f
#define WPB 4

// ws layout: [0..8): ctl {steps, ok}; [64 .. 64+B*16): per-wave masks (2 u64 each);
//            [262144 ..): z checkpoints, 2 MB per step.
#define WS_MASK_OFF 64
#define WS_Z_OFF    262144

__device__ __forceinline__ float bcastf(float v, int l) {
    return __int_as_float(__builtin_amdgcn_readlane(__float_as_int(v), l));
}

// MODE 0: run mi steps from z0; store z_k (k<=zcap); record per-step global-residual bits.
// MODE 1: fallback replay (only if ctl[1]==0): run ctl[0] steps, write out.
template <int MODE>
__global__ __launch_bounds__(256, 5) void dys_pass(
    const float* __restrict__ u_nom,     // (B,16)
    const float* __restrict__ Amat,      // (B,32,16)
    const float* __restrict__ bvec,      // (B,32)
    const int*   __restrict__ mi_ptr,
    const int*   __restrict__ ctl,       // {steps, stored_ok}
    unsigned long long* __restrict__ wmasks,
    float*       __restrict__ zstore,
    int zcap,
    float*       __restrict__ out,
    int B)
{
    if (MODE == 1) { if (ctl[1]) return; }   // stored path: gather handles output

    const int tid   = threadIdx.x;
    const int lane  = tid & 63;
    const int wib   = tid >> 6;
    const int elem  = blockIdx.x * WPB + wib;
    const int row32 = lane & 31;
    const int col16 = lane & 15;

    // ---- load A row (dup on upper half), u, b ----
    const float* Ab = Amat + (size_t)elem * 512 + (size_t)row32 * 16;
    float A_row[16];
    {
        float4 a0 = ((const float4*)Ab)[0];
        float4 a1 = ((const float4*)Ab)[1];
        float4 a2 = ((const float4*)Ab)[2];
        float4 a3 = ((const float4*)Ab)[3];
        A_row[0]=a0.x;  A_row[1]=a0.y;  A_row[2]=a0.z;  A_row[3]=a0.w;
        A_row[4]=a1.x;  A_row[5]=a1.y;  A_row[6]=a1.z;  A_row[7]=a1.w;
        A_row[8]=a2.x;  A_row[9]=a2.y;  A_row[10]=a2.z; A_row[11]=a2.w;
        A_row[12]=a3.x; A_row[13]=a3.y; A_row[14]=a3.z; A_row[15]=a3.w;
    }
    const float un = u_nom[(size_t)elem * 16 + col16];
    const float bv = bvec[(size_t)elem * 32 + row32];

    // W layout per lane:
    //   lanes 0-31  (i=lane&15 after overwrite): [AtQA_i(16) | AtQ_i(32)]
    //   lanes 32-63 (j=lane-32):                 [QA_j(16)   | Q_j(32)  ]
    float W[48];

    // ---- N = 2*A*A^T + I : every lane builds row (lane&31) in W[16..47] ----
    {
        float A2[16];
        #pragma unroll
        for (int k = 0; k < 16; ++k) A2[k] = A_row[k] + A_row[k];
        #pragma unroll
        for (int j = 0; j < 32; ++j) {
            float acc = (row32 == j) ? 1.f : 0.f;
            #pragma unroll
            for (int k = 0; k < 16; ++k)
                acc = fmaf(A2[k], bcastf(A_row[k], j), acc);
            W[16 + j] = acc;
        }
    }

    // ---- in-place Gauss-Jordan inversion of N (SPD, eigs >= 1, no pivoting) ----
    // All 64 lanes run it (upper half duplicates) -> Q row (lane&31) lands everywhere.
    #pragma unroll
    for (int p = 0; p < 32; ++p) {
        float piv = bcastf(W[16 + p], p);
        float d = __builtin_amdgcn_rcpf(piv);
        d = d * (2.f - piv * d);                    // one Newton step
        float g = W[16 + p] * d;
        g = (row32 == p) ? (1.f - d) : g;
        float negg = -g;
        #pragma unroll
        for (int j = 0; j < 32; ++j) {
            if (j == p) continue;
            float spj = bcastf(W[16 + j], p);       // OLD pivot-row value
            W[16 + j] = fmaf(negg, spj, W[16 + j]);
        }
        W[16 + p] = (row32 == p) ? d : negg;
    }

    // ---- QA row (lane&31) into W[0..15] on all lanes ----
    #pragma unroll
    for (int k = 0; k < 16; ++k) W[k] = 0.f;
    #pragma unroll
    for (int m = 0; m < 32; ++m) {
        float q = W[16 + m];
        #pragma unroll
        for (int k = 0; k < 16; ++k)
            W[k] = fmaf(q, bcastf(A_row[k], m), W[k]);
    }

    // ---- lanes 0-31: build AtQA (via LDS-staged A) and AtQ = (QA)^T (via LDS transpose)
    __shared__ float ldsT[WPB][32 * 17];
    float* T = ldsT[wib];

    if (lane < 32) {
        #pragma unroll
        for (int k = 0; k < 16; ++k) T[row32 * 17 + k] = A_row[k];
    }
    __syncthreads();

    float tq[16];
    #pragma unroll
    for (int k = 0; k < 16; ++k) tq[k] = 0.f;
    #pragma unroll
    for (int m = 0; m < 32; ++m) {
        float a_mi = T[m * 17 + col16];             // A[m][i], i = lane&15
        #pragma unroll
        for (int k = 0; k < 16; ++k)
            tq[k] = fmaf(a_mi, bcastf(W[k], m), tq[k]);   // * QA[m][k]
    }
    __syncthreads();

    if (lane < 32) {
        #pragma unroll
        for (int k = 0; k < 16; ++k) T[row32 * 17 + k] = W[k];   // stage QA rows
    }
    __syncthreads();
    if (lane < 32) {
        #pragma unroll
        for (int m = 0; m < 32; ++m) W[16 + m] = T[m * 17 + col16];  // AtQ[i][m] = QA[m][i]
        #pragma unroll
        for (int k = 0; k < 16; ++k) W[k] = tq[k];                   // AtQA row i
    }

    // ---- folded constant: c = (lanes<32 ? AtQ.b : Q.b) ----
    float c = 0.f;
    #pragma unroll
    for (int m = 0; m < 32; ++m) c = fmaf(W[16 + m], bcastf(bv, m), c);
    const float cneg = -c;

    const float sgn = (lane >= 16 && lane < 32) ? 1.f : -1.f;

    const int mi = *mi_ptr;
    const int nsteps = (MODE == 0) ? mi : ctl[0];

    float* zp = zstore + (size_t)elem * 64 + lane;
    const size_t zstride = (size_t)B * 64;

    float z = 0.f;
    unsigned long long m0 = 0ull, m1 = 0ull, b0 = 1ull, b1 = 0ull;

    for (int k = 1; k <= nsteps; ++k) {
        float x   = fmaxf(z, 0.f);
        float x16 = __shfl(x, lane + 16);
        float z16 = __shfl(z, lane + 16);
        float t1  = x - x16;
        float s   = t1 - (z - z16) + un;            // lanes 0-15 valid
        float e   = t1 - un;                        // lanes 0-15 valid
        float h   = fmaf(2.f, x, -z);               // lanes 32-63 valid

        float acc0 = cneg, acc1 = 0.f;
        #pragma unroll
        for (int m = 0; m < 16; m += 2) {
            acc0 = fmaf(W[m],     bcastf(s, m),     acc0);
            acc1 = fmaf(W[m + 1], bcastf(s, m + 1), acc1);
        }
        #pragma unroll
        for (int m = 0; m < 32; m += 2) {
            acc0 = fmaf(W[16 + m], bcastf(h, 32 + m), acc0);
            acc1 = fmaf(W[17 + m], bcastf(h, 33 + m), acc1);
        }
        float acc = acc0 + acc1;    // lanes 0-31: At.w ; lanes 32-63: w

        float ee = __shfl(e, col16);
        float q  = fmaf(0.5f, ee, acc);
        float t  = (lane < 32) ? q : acc;
        float znew = fmaf(sgn, t, x);

        if (MODE == 0) {
            unsigned long long cy = b0 >> 63;
            b0 <<= 1; b1 = (b1 << 1) | cy;          // b = 1 << k
            float r = fabsf(znew - z);
            if (r >= TOL) { m0 |= b0; m1 |= b1; }
            if (k <= zcap) { *zp = znew; zp += zstride; }
        }
        z = znew;
    }

    if (MODE == 0) {
        #pragma unroll
        for (int off = 32; off; off >>= 1) {
            m0 |= __shfl_xor(m0, off);
            m1 |= __shfl_xor(m1, off);
        }
        if (lane == 0) { wmasks[2 * elem] = m0; wmasks[2 * elem + 1] = m1; }
    } else {
        float z16b = __shfl(z, lane + 16);
        if (lane < 16) out[(size_t)elem * 16 + lane] = z - z16b;
        out[(size_t)B * 16 + (size_t)elem * 64 + lane] = z;
    }
}

// Global stop step: S = (first k in [1,mi) with no lane anywhere >= TOL) + 1, else mi.
__global__ __launch_bounds__(256) void dys_reduce(
    const int* __restrict__ mi_ptr,
    const unsigned long long* __restrict__ wmasks,
    int nwaves, int zcap, int* __restrict__ ctl)
{
    __shared__ unsigned long long sm0[4], sm1[4];
    unsigned long long m0 = 0ull, m1 = 0ull;
    for (int i = threadIdx.x; i < nwaves; i += 256) {
        m0 |= wmasks[2 * i];
        m1 |= wmasks[2 * i + 1];
    }
    #pragma unroll
    for (int off = 32; off; off >>= 1) {
        m0 |= __shfl_xor(m0, off);
        m1 |= __shfl_xor(m1, off);
    }
    int wv = threadIdx.x >> 6;
    if ((threadIdx.x & 63) == 0) { sm0[wv] = m0; sm1[wv] = m1; }
    __syncthreads();
    if (threadIdx.x == 0) {
        m0 = sm0[0] | sm0[1] | sm0[2] | sm0[3];
        m1 = sm1[0] | sm1[1] | sm1[2] | sm1[3];
        int mi = *mi_ptr;
        int S = mi;                                  // masks cover k<128; mi<=100 here
        for (int k = 1; k < mi && k < 128; ++k) {
            unsigned long long bit = (k < 64) ? ((m0 >> k) & 1ull)
                                              : ((m1 >> (k - 64)) & 1ull);
            if (!bit) { S = k + 1; break; }
        }
        ctl[0] = S;
        ctl[1] = (S <= zcap) ? 1 : 0;
    }
}

__global__ __launch_bounds__(256) void dys_gather(
    const int* __restrict__ ctl, const float* __restrict__ zstore,
    float* __restrict__ out, int B)
{
    if (!ctl[1]) return;
    int tid  = blockIdx.x * 256 + threadIdx.x;
    int lane = tid & 63;
    int elem = tid >> 6;
    int S = ctl[0];
    float z = zstore[(size_t)(S - 1) * B * 64 + (size_t)elem * 64 + lane];
    float z16 = __shfl(z, lane + 16);
    if (lane < 16) out[(size_t)elem * 16 + lane] = z - z16;
    out[(size_t)B * 16 + (size_t)elem * 64 + lane] = z;
}

extern "C" void kernel_launch(void* const* d_in, const int* in_sizes, int n_in,
                              void* d_out, int out_size, void* d_ws, size_t ws_size,
                              hipStream_t stream) {
    (void)n_in; (void)out_size;
    const float* u_nom = (const float*)d_in[0];
    const float* Amat  = (const float*)d_in[1];
    const float* bvec  = (const float*)d_in[2];
    const int*   mi    = (const int*)d_in[3];

    const int B = in_sizes[0] / 16;                  // 8192

    int* ctl = (int*)d_ws;
    unsigned long long* wmasks = (unsigned long long*)((char*)d_ws + WS_MASK_OFF);
    float* zstore = (float*)((char*)d_ws + WS_Z_OFF);

    const size_t stepBytes = (size_t)B * 64 * sizeof(float);   // 2 MB
    int zcap = 0;
    if (ws_size > WS_Z_OFF + stepBytes)
        zcap = (int)((ws_size - WS_Z_OFF) / stepBytes);
    if (zcap > 127) zcap = 127;                      // masks cover k<128

    const int blocks = B / WPB;
    dys_pass<0><<<blocks, 64 * WPB, 0, stream>>>(u_nom, Amat, bvec, mi, ctl,
                                                 wmasks, zstore, zcap, (float*)d_out, B);
    dys_reduce<<<1, 256, 0, stream>>>(mi, wmasks, B, zcap, ctl);
    // Fallback replay (early-exits when checkpoints are valid):
    dys_pass<1><<<blocks, 64 * WPB, 0, stream>>>(u_nom, Amat, bvec, mi, ctl,
                                                 wmasks, zstore, zcap, (float*)d_out, B);
    // Checkpoint gather (early-exits when fallback ran):
    dys_gather<<<B * 64 / 256, 256, 0, stream>>>(ctl, zstore, (float*)d_out, B);
}

// Round 3
// 307.003 us; speedup vs baseline: 2.5500x; 1.0366x over previous
//
#include <hip/hip_runtime.h>
#include <stdint.h>

#define TOL 1e-2f
#define WPB 4
// ws layout: [0..128): 8 hashed flag slots (2 u64 each); [192..200): ctl {S, ok};
//            [4096..): z checkpoints, one 2 MB slab per step.
#define WS_CTL_OFF 192
#define WS_Z_OFF   4096

typedef float f32x2 __attribute__((ext_vector_type(2)));

__device__ __forceinline__ float bcastf(float v, int l) {
    return __int_as_float(__builtin_amdgcn_readlane(__float_as_int(v), l));
}

// MODE 0: run mi steps from z0; store z_k checkpoints; OR per-step (res>=TOL) bits
//         into hashed global flag slots.
// MODE 1: fallback replay (only if ctl[1]==0): run ctl[0] steps, write out.
template <int MODE>
__global__ __launch_bounds__(256, 4) void dys_pass(
    const float* __restrict__ u_nom,     // (B,16)
    const float* __restrict__ Amat,      // (B,32,16)
    const float* __restrict__ bvec,      // (B,32)
    const int*   __restrict__ mi_ptr,
    const int*   __restrict__ ctl,       // {S, stored_ok}
    unsigned long long* __restrict__ flags,
    float*       __restrict__ zstore,
    int zcap,
    float*       __restrict__ out,
    int B)
{
    if (MODE == 1) { if (ctl[1]) return; }   // checkpoint path valid: gather handles out

    const int tid   = threadIdx.x;
    const int lane  = tid & 63;
    const int wib   = tid >> 6;
    const int elem  = blockIdx.x * WPB + wib;
    const int row32 = lane & 31;
    const int col16 = lane & 15;

    __shared__ float ldsT[WPB][32 * 17];
    float* T = ldsT[wib];

    // ---- load A row (dup on upper half), u, b ----
    const float* Ab = Amat + (size_t)elem * 512 + (size_t)row32 * 16;
    float A_row[16];
    {
        float4 a0 = ((const float4*)Ab)[0];
        float4 a1 = ((const float4*)Ab)[1];
        float4 a2 = ((const float4*)Ab)[2];
        float4 a3 = ((const float4*)Ab)[3];
        A_row[0]=a0.x;  A_row[1]=a0.y;  A_row[2]=a0.z;  A_row[3]=a0.w;
        A_row[4]=a1.x;  A_row[5]=a1.y;  A_row[6]=a1.z;  A_row[7]=a1.w;
        A_row[8]=a2.x;  A_row[9]=a2.y;  A_row[10]=a2.z; A_row[11]=a2.w;
        A_row[12]=a3.x; A_row[13]=a3.y; A_row[14]=a3.z; A_row[15]=a3.w;
    }
    if (lane < 32) {
        #pragma unroll
        for (int k = 0; k < 16; ++k) T[row32 * 17 + k] = A_row[k];
    }
    const float un = u_nom[(size_t)elem * 16 + col16];
    const float bv = bvec[(size_t)elem * 32 + row32];

    // ---- N = 2*A*A^T + I: row (lane&31) on every lane ----
    float Wh[32];
    {
        float A2[16];
        #pragma unroll
        for (int k = 0; k < 16; ++k) A2[k] = A_row[k] + A_row[k];
        #pragma unroll
        for (int j = 0; j < 32; ++j) {
            float acc = (row32 == j) ? 1.f : 0.f;
            #pragma unroll
            for (int k = 0; k < 16; ++k)
                acc = fmaf(A2[k], bcastf(A_row[k], j), acc);
            Wh[j] = acc;
        }
    }

    // ---- in-place Gauss-Jordan: Wh becomes Q = N^-1 row (lane&31) ----
    #pragma unroll
    for (int p = 0; p < 32; ++p) {
        float piv = bcastf(Wh[p], p);
        float d = __builtin_amdgcn_rcpf(piv);
        d = d * (2.f - piv * d);
        float g = Wh[p] * d;
        g = (row32 == p) ? (1.f - d) : g;
        float negg = -g;
        #pragma unroll
        for (int j = 0; j < 32; ++j) {
            if (j == p) continue;
            float spj = bcastf(Wh[j], p);
            Wh[j] = fmaf(negg, spj, Wh[j]);
        }
        Wh[p] = (row32 == p) ? d : negg;
    }

    // ---- QA row (lane&31) ----
    float qa[16];
    #pragma unroll
    for (int k = 0; k < 16; ++k) qa[k] = 0.f;
    #pragma unroll
    for (int m = 0; m < 32; ++m) {
        float q = Wh[m];
        #pragma unroll
        for (int k = 0; k < 16; ++k)
            qa[k] = fmaf(q, bcastf(A_row[k], m), qa[k]);
    }

    // ---- pack: W2[0..7] <- s-side matrix rows; W2[8..23] <- h-side ----
    f32x2 W2[24];
    #pragma unroll
    for (int t = 0; t < 16; ++t) { f32x2 v = {Wh[2*t], Wh[2*t+1]}; W2[8+t] = v; }

    __syncthreads();

    // ---- lanes 0-31: AtQA row i = col16 (via A staged in T, QA broadcasts) ----
    float tq[16];
    #pragma unroll
    for (int k = 0; k < 16; ++k) tq[k] = 0.f;
    #pragma unroll
    for (int m = 0; m < 32; ++m) {
        float a_mi = T[m * 17 + col16];          // A[m][i]
        #pragma unroll
        for (int k = 0; k < 16; ++k)
            tq[k] = fmaf(a_mi, bcastf(qa[k], m), tq[k]);   // * QA[m][k]
    }
    __syncthreads();

    if (lane < 32) {
        #pragma unroll
        for (int k = 0; k < 16; ++k) T[row32 * 17 + k] = qa[k];   // stage QA rows
    }
    __syncthreads();

    if (lane < 32) {
        #pragma unroll
        for (int t = 0; t < 16; ++t) {           // AtQ[i][m] = QA[m][i]
            f32x2 v;
            v.x = T[(2*t)   * 17 + col16];
            v.y = T[(2*t+1) * 17 + col16];
            W2[8+t] = v;
        }
        #pragma unroll
        for (int t = 0; t < 8; ++t) { f32x2 v = {tq[2*t], tq[2*t+1]}; W2[t] = v; }
    } else {
        #pragma unroll
        for (int t = 0; t < 8; ++t) { f32x2 v = {qa[2*t], qa[2*t+1]}; W2[t] = v; }
    }

    // ---- fold c = (lanes<32 ? AtQ.b : Q.b) ----
    float cneg;
    {
        f32x2 cc = {0.f, 0.f};
        #pragma unroll
        for (int t = 0; t < 16; ++t) {
            f32x2 bb = {bcastf(bv, 2*t), bcastf(bv, 2*t+1)};
            cc = W2[8+t] * bb + cc;
        }
        cneg = -(cc.x + cc.y);
    }

    const float sgn = (lane >= 16 && lane < 32) ? 1.f : -1.f;

    const int mi = *mi_ptr;
    const int nsteps = (MODE == 0) ? mi : ctl[0];

    float* zp = zstore + (size_t)elem * 64 + lane;
    const size_t zstride = (size_t)B * 64;

    float z = 0.f;
    unsigned long long m0 = 0ull, m1 = 0ull, b0 = 1ull, b1 = 0ull;

    for (int k = 1; k <= nsteps; ++k) {
        float x   = fmaxf(z, 0.f);
        float x16 = __shfl(x, lane + 16);
        float z16 = __shfl(z, lane + 16);
        float t1  = x - x16;
        float s   = t1 - (z - z16) + un;            // lanes 0-15 valid
        float e   = t1 - un;                        // lanes 0-15 valid
        float h   = fmaf(2.f, x, -z);               // lanes 32-63 valid

        f32x2 a0 = {cneg, 0.f}, a1 = {0.f, 0.f}, a2 = {0.f, 0.f}, a3 = {0.f, 0.f};
        #pragma unroll
        for (int t = 0; t < 8; t += 4) {
            f32x2 p0 = {bcastf(s, 2*t),   bcastf(s, 2*t+1)};
            f32x2 p1 = {bcastf(s, 2*t+2), bcastf(s, 2*t+3)};
            f32x2 p2 = {bcastf(s, 2*t+4), bcastf(s, 2*t+5)};
            f32x2 p3 = {bcastf(s, 2*t+6), bcastf(s, 2*t+7)};
            a0 = W2[t]   * p0 + a0;
            a1 = W2[t+1] * p1 + a1;
            a2 = W2[t+2] * p2 + a2;
            a3 = W2[t+3] * p3 + a3;
        }
        #pragma unroll
        for (int t = 8; t < 24; t += 4) {
            f32x2 p0 = {bcastf(h, 2*t+16), bcastf(h, 2*t+17)};
            f32x2 p1 = {bcastf(h, 2*t+18), bcastf(h, 2*t+19)};
            f32x2 p2 = {bcastf(h, 2*t+20), bcastf(h, 2*t+21)};
            f32x2 p3 = {bcastf(h, 2*t+22), bcastf(h, 2*t+23)};
            a0 = W2[t]   * p0 + a0;
            a1 = W2[t+1] * p1 + a1;
            a2 = W2[t+2] * p2 + a2;
            a3 = W2[t+3] * p3 + a3;
        }
        f32x2 asum = (a0 + a1) + (a2 + a3);
        float acc = asum.x + asum.y;

        float ee = __shfl(e, col16);
        float t  = (lane < 32) ? fmaf(0.5f, ee, acc) : acc;
        float znew = fmaf(sgn, t, x);

        if (MODE == 0) {
            unsigned long long cy = b0 >> 63;
            b0 <<= 1; b1 = (b1 << 1) | cy;                       // b = 1 << k (uniform, SALU)
            unsigned long long any = __ballot(fabsf(znew - z) >= TOL);
            if (any) { m0 |= b0; m1 |= b1; }
            if (k <= zcap) { *zp = znew; zp += zstride; }
        }
        z = znew;
    }

    if (MODE == 0) {
        if (lane == 0) {
            int slot = blockIdx.x & 7;
            atomicOr(flags + 2 * slot,     m0);
            atomicOr(flags + 2 * slot + 1, m1);
        }
    } else {
        float z16b = __shfl(z, lane + 16);
        if (lane < 16) out[(size_t)elem * 16 + lane] = z - z16b;
        out[(size_t)B * 16 + (size_t)elem * 64 + lane] = z;
    }
}

// S = (first k in [1,mi) with global residual < TOL) + 1, else mi.
__global__ void dys_reduce(const int* __restrict__ mi_ptr,
                           const unsigned long long* __restrict__ flags,
                           int zcap, int* __restrict__ ctl)
{
    if (threadIdx.x != 0) return;
    unsigned long long m0 = 0ull, m1 = 0ull;
    for (int s = 0; s < 8; ++s) { m0 |= flags[2*s]; m1 |= flags[2*s+1]; }
    int mi = *mi_ptr;
    int S = mi;
    for (int k = 1; k < mi && k < 128; ++k) {
        unsigned long long bit = (k < 64) ? ((m0 >> k) & 1ull)
                                          : ((m1 >> (k - 64)) & 1ull);
        if (!bit) { S = k + 1; break; }
    }
    if (S < 1) S = 1;
    ctl[0] = S;
    ctl[1] = (S <= zcap) ? 1 : 0;
}

__global__ __launch_bounds__(256) void dys_gather(
    const int* __restrict__ ctl, const float* __restrict__ zstore,
    float* __restrict__ out, int B)
{
    if (!ctl[1]) return;
    int tid  = blockIdx.x * 256 + threadIdx.x;
    int lane = tid & 63;
    int elem = tid >> 6;
    int S = ctl[0];
    float z = zstore[(size_t)(S - 1) * B * 64 + (size_t)elem * 64 + lane];
    float z16 = __shfl(z, lane + 16);
    if (lane < 16) out[(size_t)elem * 16 + lane] = z - z16;
    out[(size_t)B * 16 + (size_t)elem * 64 + lane] = z;
}

extern "C" void kernel_launch(void* const* d_in, const int* in_sizes, int n_in,
                              void* d_out, int out_size, void* d_ws, size_t ws_size,
                              hipStream_t stream) {
    (void)n_in; (void)out_size;
    const float* u_nom = (const float*)d_in[0];
    const float* Amat  = (const float*)d_in[1];
    const float* bvec  = (const float*)d_in[2];
    const int*   mi    = (const int*)d_in[3];

    const int B = in_sizes[0] / 16;                  // 8192

    unsigned long long* flags = (unsigned long long*)d_ws;
    int* ctl = (int*)((char*)d_ws + WS_CTL_OFF);
    float* zstore = (float*)((char*)d_ws + WS_Z_OFF);

    const size_t stepBytes = (size_t)B * 64 * sizeof(float);   // 2 MB
    int zcap = 0;
    if (ws_size > WS_Z_OFF + stepBytes)
        zcap = (int)((ws_size - WS_Z_OFF) / stepBytes);
    if (zcap > 127) zcap = 127;                      // masks cover k < 128

    hipMemsetAsync(d_ws, 0, 256, stream);            // flags + ctl

    const int blocks = B / WPB;
    dys_pass<0><<<blocks, 64 * WPB, 0, stream>>>(u_nom, Amat, bvec, mi, ctl,
                                                 flags, zstore, zcap, (float*)d_out, B);
    dys_reduce<<<1, 64, 0, stream>>>(mi, flags, zcap, ctl);
    // Fallback replay (early-exits when checkpoints cover S):
    dys_pass<1><<<blocks, 64 * WPB, 0, stream>>>(u_nom, Amat, bvec, mi, ctl,
                                                 flags, zstore, zcap, (float*)d_out, B);
    // Checkpoint gather (early-exits when fallback ran):
    dys_gather<<<B * 64 / 256, 256, 0, stream>>>(ctl, zstore, (float*)d_out, B);
}